// Round 18
// baseline (398.143 us; speedup 1.0000x reference)
//
#include <hip/hip_runtime.h>

// GeometricBlock, MI355X gfx950. CSR scatter; LDS-staged MFMA with hw-packed cvt.
// R18: edge_alpha single-buffer LDS (H only, 33792B -> 4 blk/CU = 32 waves, 100%):
// ef-stage, hidden, chi-stage, w all time-share H. Same 7 barriers as R15.
// node_qk 8-wave + gather skip-dead-loads kept from R17 (both validated).

typedef short bf16x8 __attribute__((ext_vector_type(8)));
typedef float f32x4 __attribute__((ext_vector_type(4)));
typedef unsigned short u16;
typedef u16 u16x8 __attribute__((ext_vector_type(8)));

__device__ __forceinline__ float bf2f(u16 h) {
  return __builtin_bit_cast(float, ((unsigned)h) << 16);
}
__device__ __forceinline__ unsigned cvt_pk_bf16(float lo, float hi) {
  unsigned p;
  asm("v_cvt_pk_bf16_f32 %0, %1, %2" : "=v"(p) : "v"(lo), "v"(hi));
  return p;
}
__device__ __forceinline__ u16 f2bf_hw(float f) {
  return (u16)cvt_pk_bf16(f, f);
}
__device__ __forceinline__ float silu_fast(float x) {
  return x * __builtin_amdgcn_rcpf(1.f + __expf(-x));
}

// ---------------- pack weights to MFMA B-fragment order ---------------------
__global__ __launch_bounds__(256) void pack_kernel(
    const float* __restrict__ W1, const float* __restrict__ W2,
    const float* __restrict__ Wsp, const float* __restrict__ Wq,
    const float* __restrict__ Wk, const float* __restrict__ b2,
    const float* __restrict__ bs, u16* __restrict__ W1p,
    u16* __restrict__ W23p, u16* __restrict__ Wqkp, float* __restrict__ b23) {
  int t = blockIdx.x * 256 + threadIdx.x;
  if (t < 2048) {  // W1: K=64 (KF=2), C=256
    int lane = t & 63, kf = (t >> 6) & 1, cf = t >> 7;
    int kb = kf * 32 + ((lane >> 4) << 3), c = cf * 16 + (lane & 15);
    u16x8 o;
#pragma unroll
    for (int j = 0; j < 8; j++) o[j] = f2bf_hw(W1[(kb + j) * 256 + c]);
    *reinterpret_cast<u16x8*>(W1p + (((cf * 2 + kf) * 64 + lane) << 3)) = o;
  } else if (t < 14336) {  // W23: K=384 (KF=12), C=256
    int u = t - 2048;
    int lane = u & 63, f = u >> 6, kf = f % 12, cf = f / 12;
    int kb = kf * 32 + ((lane >> 4) << 3), c = cf * 16 + (lane & 15);
    u16x8 o;
#pragma unroll
    for (int j = 0; j < 8; j++) {
      int k = kb + j;
      float v = (k < 256) ? W2[k * 256 + c] : Wsp[(k - 256) * 256 + c];
      o[j] = f2bf_hw(v);
    }
    *reinterpret_cast<u16x8*>(W23p + (((cf * 12 + kf) * 64 + lane) << 3)) = o;
  } else if (t < 30720) {  // Wqk: K=256 (KF=8), C=512
    int u = t - 14336;
    int lane = u & 63, f = u >> 6, kf = f & 7, cf = f >> 3;
    int kb = kf * 32 + ((lane >> 4) << 3), c = cf * 16 + (lane & 15);
    u16x8 o;
#pragma unroll
    for (int j = 0; j < 8; j++) {
      int k = kb + j;
      float v = (c < 256) ? Wq[k * 256 + c] : Wk[k * 256 + (c - 256)];
      o[j] = f2bf_hw(v);
    }
    *reinterpret_cast<u16x8*>(Wqkp + (((cf * 8 + kf) * 64 + lane) << 3)) = o;
  } else if (t < 30976) {
    int c = t - 30720;
    b23[c] = b2[c] + bs[c];
  }
}

// ---------------- qk[n] = node_feats[n] @ [Wq|Wk], bf16 out -----------------
// 512 threads / 8 waves; wave owns 32 cols per nh pass (acc[4][2], low VGPR).
__global__ __launch_bounds__(512) void node_qk_kernel(
    const float* __restrict__ nf, const u16* __restrict__ Wqkp,
    u16* __restrict__ qk, int N) {
  __shared__ u16 A[64 * 264];
  const int t = threadIdx.x;
  const int nb0 = blockIdx.x * 64;
#pragma unroll
  for (int p = 0; p < 8; p++) {
    int r = p * 8 + (t >> 6), c4 = t & 63;
    int row = nb0 + r;
    float4 v = make_float4(0.f, 0.f, 0.f, 0.f);
    if (row < N) v = *reinterpret_cast<const float4*>(nf + (size_t)row * 256 + c4 * 4);
    uint2 o;
    o.x = cvt_pk_bf16(v.x, v.y);
    o.y = cvt_pk_bf16(v.z, v.w);
    *reinterpret_cast<uint2*>(&A[r * 264 + c4 * 4]) = o;
  }
  __syncthreads();
  const int lane = t & 63, wv = t >> 6;
  const int l15 = lane & 15, lhi = lane >> 4;
  for (int nh = 0; nh < 2; nh++) {
    const int colbase = nh * 256 + wv * 32;
    f32x4 acc[4][2];
#pragma unroll
    for (int m = 0; m < 4; m++)
#pragma unroll
      for (int n = 0; n < 2; n++) acc[m][n] = f32x4{0.f, 0.f, 0.f, 0.f};
#pragma unroll
    for (int kf = 0; kf < 8; kf++) {
      bf16x8 a[4];
#pragma unroll
      for (int m = 0; m < 4; m++)
        a[m] = *reinterpret_cast<const bf16x8*>(&A[(m * 16 + l15) * 264 + kf * 32 + lhi * 8]);
#pragma unroll
      for (int n = 0; n < 2; n++) {
        int cf = (colbase >> 4) + n;
        bf16x8 b = *reinterpret_cast<const bf16x8*>(Wqkp + (((cf * 8 + kf) * 64 + lane) << 3));
#pragma unroll
        for (int m = 0; m < 4; m++)
          acc[m][n] = __builtin_amdgcn_mfma_f32_16x16x32_bf16(a[m], b, acc[m][n], 0, 0, 0);
      }
    }
#pragma unroll
    for (int m = 0; m < 4; m++) {
      int row = nb0 + m * 16 + lhi * 4;
#pragma unroll
      for (int n = 0; n < 2; n++) {
        int col = colbase + n * 16 + l15;
#pragma unroll
        for (int j = 0; j < 4; j++) {
          if (row + j < N) qk[(size_t)(row + j) * 512 + col] = f2bf_hw(acc[m][n][j]);
        }
      }
    }
  }
}

// ---------------- edge alpha: GEMMs + q.w.k -> alpha[E,32] ------------------
// 64 edges/block, 512 threads / 8 waves; wave owns 32 cols (acc[4][2]).
// Single LDS buffer H (33792B -> 4 blk/CU): ef / hidden / chi / w time-share it.
__global__ __launch_bounds__(512) void edge_alpha_kernel(
    const float* __restrict__ edge_feats, const float* __restrict__ chi_s,
    const float* __restrict__ cutoffs, const int* __restrict__ senders,
    const int* __restrict__ receivers, const u16* __restrict__ W1p,
    const u16* __restrict__ W23p, const float* __restrict__ b1,
    const float* __restrict__ b23, const u16* __restrict__ qk,
    void* __restrict__ alpha_out, int alpha_f32, int E) {
  __shared__ u16 H[64 * 264];  // row 528B; only LDS buffer

  const int t = threadIdx.x;
  const int e0 = blockIdx.x * 64;
  const int lane = t & 63, wv = t >> 6, l15 = lane & 15, lhi = lane >> 4;
  const int koff = lhi * 8;
  const int sr = t >> 3;                      // staging row (0..63)
  const int se = (e0 + sr < E) ? e0 + sr : (E - 1);

  // ---- ph1: stage edge_feats [64][64] f32 -> bf16 into H cols 0..63
  {
    const int sc8 = (t & 7) * 8;
    const float* src = edge_feats + (size_t)se * 64 + sc8;
#pragma unroll
    for (int q = 0; q < 2; q++) {
      float4 v = *reinterpret_cast<const float4*>(src + q * 4);
      uint2 o;
      o.x = cvt_pk_bf16(v.x, v.y);
      o.y = cvt_pk_bf16(v.z, v.w);
      *reinterpret_cast<uint2*>(&H[sr * 264 + sc8 + q * 4]) = o;
    }
  }
  __syncthreads();  // (1) ef staged

  f32x4 acc[4][2];
  // ---- ph2: GEMM1 reads ef from H
#pragma unroll
  for (int m = 0; m < 4; m++)
#pragma unroll
    for (int n = 0; n < 2; n++) acc[m][n] = f32x4{0.f, 0.f, 0.f, 0.f};
#pragma unroll
  for (int kf = 0; kf < 2; kf++) {
    bf16x8 a[4];
#pragma unroll
    for (int m = 0; m < 4; m++)
      a[m] = *reinterpret_cast<const bf16x8*>(&H[(m * 16 + l15) * 264 + kf * 32 + koff]);
#pragma unroll
    for (int n = 0; n < 2; n++) {
      int cf = wv * 2 + n;
      bf16x8 b = *reinterpret_cast<const bf16x8*>(W1p + (((cf * 2 + kf) * 64 + lane) << 3));
#pragma unroll
      for (int m = 0; m < 4; m++)
        acc[m][n] = __builtin_amdgcn_mfma_f32_16x16x32_bf16(a[m], b, acc[m][n], 0, 0, 0);
    }
  }
  __syncthreads();  // (2) all ef reads done -> H reusable
  // ---- ph3: hidden = silu(acc + b1) -> H (all 256 cols)
  {
    float bv[2];
#pragma unroll
    for (int n = 0; n < 2; n++) bv[n] = b1[wv * 32 + n * 16 + l15];
#pragma unroll
    for (int m = 0; m < 4; m++)
#pragma unroll
      for (int n = 0; n < 2; n++) {
        int col = wv * 32 + n * 16 + l15;
#pragma unroll
        for (int jp = 0; jp < 2; jp++) {
          float x0 = silu_fast(acc[m][n][jp * 2] + bv[n]);
          float x1 = silu_fast(acc[m][n][jp * 2 + 1] + bv[n]);
          unsigned p = cvt_pk_bf16(x0, x1);
          int row = m * 16 + lhi * 4 + jp * 2;
          H[row * 264 + col] = (u16)p;
          H[(row + 1) * 264 + col] = (u16)(p >> 16);
        }
      }
  }
  __syncthreads();  // (3) hidden visible
  // ---- ph4: GEMM2 (hidden K=256 from H)
#pragma unroll
  for (int m = 0; m < 4; m++)
#pragma unroll
    for (int n = 0; n < 2; n++) acc[m][n] = f32x4{0.f, 0.f, 0.f, 0.f};
#pragma unroll
  for (int kf = 0; kf < 8; kf++) {
    bf16x8 a[4];
#pragma unroll
    for (int m = 0; m < 4; m++)
      a[m] = *reinterpret_cast<const bf16x8*>(&H[(m * 16 + l15) * 264 + kf * 32 + koff]);
#pragma unroll
    for (int n = 0; n < 2; n++) {
      int cf = wv * 2 + n;
      bf16x8 b = *reinterpret_cast<const bf16x8*>(W23p + (((cf * 12 + kf) * 64 + lane) << 3));
#pragma unroll
      for (int m = 0; m < 4; m++)
        acc[m][n] = __builtin_amdgcn_mfma_f32_16x16x32_bf16(a[m], b, acc[m][n], 0, 0, 0);
    }
  }
  __syncthreads();  // (4) hidden reads done -> H reusable
  // ---- ph5: stage chi [64][128] -> H cols 0..127
  {
    const int sc16 = (t & 7) * 16;
    const float* src = chi_s + (size_t)se * 128 + sc16;
#pragma unroll
    for (int q = 0; q < 4; q++) {
      float4 v = *reinterpret_cast<const float4*>(src + q * 4);
      uint2 o;
      o.x = cvt_pk_bf16(v.x, v.y);
      o.y = cvt_pk_bf16(v.z, v.w);
      *reinterpret_cast<uint2*>(&H[sr * 264 + sc16 + q * 4]) = o;
    }
  }
  __syncthreads();  // (5) chi staged
  // ---- ph6: GEMM3 (chi K=128 from H), accumulating into acc
#pragma unroll
  for (int kf = 0; kf < 4; kf++) {
    bf16x8 a[4];
#pragma unroll
    for (int m = 0; m < 4; m++)
      a[m] = *reinterpret_cast<const bf16x8*>(&H[(m * 16 + l15) * 264 + kf * 32 + koff]);
#pragma unroll
    for (int n = 0; n < 2; n++) {
      int cf = wv * 2 + n;
      bf16x8 b = *reinterpret_cast<const bf16x8*>(W23p + (((cf * 12 + 8 + kf) * 64 + lane) << 3));
#pragma unroll
      for (int m = 0; m < 4; m++)
        acc[m][n] = __builtin_amdgcn_mfma_f32_16x16x32_bf16(a[m], b, acc[m][n], 0, 0, 0);
    }
  }
  __syncthreads();  // (6) chi reads done -> H reusable
  // ---- ph7: w = acc + b23 -> H
  {
    float bv[2];
#pragma unroll
    for (int n = 0; n < 2; n++) bv[n] = b23[wv * 32 + n * 16 + l15];
#pragma unroll
    for (int m = 0; m < 4; m++)
#pragma unroll
      for (int n = 0; n < 2; n++) {
        int col = wv * 32 + n * 16 + l15;
#pragma unroll
        for (int jp = 0; jp < 2; jp++) {
          unsigned p = cvt_pk_bf16(acc[m][n][jp * 2] + bv[n], acc[m][n][jp * 2 + 1] + bv[n]);
          int row = m * 16 + lhi * 4 + jp * 2;
          H[row * 264 + col] = (u16)p;
          H[(row + 1) * 264 + col] = (u16)(p >> 16);
        }
      }
  }
  __syncthreads();  // (7) w visible
  // ---- ph8: alpha[e][h] = sum_d q*w*k * cutoff * (1/sqrt(8)) * (1/10)
  {
    int e = t >> 3, h8 = t & 7;
    int ee = e0 + e;
    int ec = (ee < E) ? ee : (E - 1);
    int rv = receivers[ec], sd = senders[ec];
    float sc = cutoffs[ec] * 0.035355339059327376f;  // (1/sqrt(8))*(1/10)
    const u16* qrow = qk + (size_t)rv * 512;
    const u16* krow = qk + (size_t)sd * 512 + 256;
    const bool wr = (ee < E);
    float* af = (float*)alpha_out;
    u16* ah = (u16*)alpha_out;
#pragma unroll
    for (int i = 0; i < 4; i++) {
      int h = i * 8 + h8;
      u16x8 q8 = *reinterpret_cast<const u16x8*>(qrow + h * 8);
      u16x8 k8 = *reinterpret_cast<const u16x8*>(krow + h * 8);
      u16x8 w8 = *reinterpret_cast<const u16x8*>(&H[e * 264 + h * 8]);
      float s = 0.f;
#pragma unroll
      for (int d = 0; d < 8; d++) s += bf2f(q8[d]) * bf2f(w8[d]) * bf2f(k8[d]);
      s *= sc;
      if (wr) {
        if (alpha_f32) af[(size_t)ee * 32 + h] = s;
        else ah[(size_t)ee * 32 + h] = f2bf_hw(s);
      }
    }
  }
}

// ---------------- CSR build ------------------------------------------------
__global__ __launch_bounds__(256) void hist_kernel(const int* __restrict__ recv,
                                                   int* __restrict__ counts, int E) {
  int e = blockIdx.x * 256 + threadIdx.x;
  if (e < E) atomicAdd(&counts[recv[e]], 1);
}

__global__ __launch_bounds__(256) void scan_block_kernel(int* __restrict__ counts,
                                                         int* __restrict__ bsum, int N) {
  __shared__ int tmp[256];
  int t = threadIdx.x;
  int base = blockIdx.x * 1024 + t * 4;
  int v[4], p[4], tot = 0;
#pragma unroll
  for (int j = 0; j < 4; j++) {
    int n = base + j;
    v[j] = (n < N) ? counts[n] : 0;
    p[j] = tot;
    tot += v[j];
  }
  tmp[t] = tot;
  __syncthreads();
  for (int s = 1; s < 256; s <<= 1) {
    int a = (t >= s) ? tmp[t - s] : 0;
    __syncthreads();
    tmp[t] += a;
    __syncthreads();
  }
  int excl = tmp[t] - tot;
#pragma unroll
  for (int j = 0; j < 4; j++) {
    int n = base + j;
    if (n < N) counts[n] = excl + p[j];
  }
  if (t == 255) bsum[blockIdx.x] = tmp[255];
}

__global__ void scan_top_kernel(const int* __restrict__ bsum, int* __restrict__ boff, int nb) {
  if (threadIdx.x == 0 && blockIdx.x == 0) {
    int ex = 0;
    for (int b = 0; b < nb; b++) {
      boff[b] = ex;
      ex += bsum[b];
    }
  }
}

__global__ __launch_bounds__(256) void finalize_kernel(
    const int* __restrict__ partial, const int* __restrict__ boff,
    int* __restrict__ off, int* __restrict__ cursor, int N, int E) {
  int n = blockIdx.x * 256 + threadIdx.x;
  if (n < N) {
    int o = partial[n] + boff[n >> 10];
    off[n] = o;
    cursor[n] = o;
  }
  if (n == 0) off[N] = E;
}

__global__ __launch_bounds__(256) void fill_kernel(const int* __restrict__ recv,
                                                   int* __restrict__ cursor,
                                                   int* __restrict__ eid, int E) {
  int e = blockIdx.x * 256 + threadIdx.x;
  if (e < E) {
    int pos = atomicAdd(&cursor[recv[e]], 1);
    eid[pos] = e;
  }
}

// ---------------- gather: out[n] = sum_{e in CSR(n)} sh[e] * alpha[e,hd] ----
// 8 groups x 8 lanes per wave; dead groups SKIP their loads.
__global__ __launch_bounds__(256) void gather_out_kernel(
    const float* __restrict__ edge_sh, const void* __restrict__ alpha,
    const int* __restrict__ off, const int* __restrict__ eid,
    float* __restrict__ out, int N, int alpha_f32) {
  int wv = threadIdx.x >> 6, lane = threadIdx.x & 63;
  int n = blockIdx.x * 4 + wv;
  if (n >= N) return;
  int beg = off[n], end = off[n + 1];
  int grp = lane >> 3, cl = lane & 7;
  int c0 = cl * 16;
  const float* af = (const float*)alpha;
  const u16* ah = (const u16*)alpha;
  f32x4 acc0 = {0.f, 0.f, 0.f, 0.f}, acc1 = acc0, acc2 = acc0, acc3 = acc0;
  int i = beg;
  while (i < end) {
    int cnt = end - i;
    if (cnt > 64) cnt = 64;
    int ev = eid[i + ((lane < cnt) ? lane : 0)];  // one coalesced eid load
    for (int k = 0; k < cnt; k += 8) {
      int idx = k + grp;
      int ea = __shfl(ev, (idx < cnt) ? idx : 0);  // shfl outside branch
      if (idx < cnt) {
        const float* shp = edge_sh + (size_t)ea * 128 + c0;
        float4 s0 = *reinterpret_cast<const float4*>(shp);
        float4 s1 = *reinterpret_cast<const float4*>(shp + 4);
        float4 s2 = *reinterpret_cast<const float4*>(shp + 8);
        float4 s3 = *reinterpret_cast<const float4*>(shp + 12);
        float a0, a1, a2, a3;
        if (alpha_f32) {
          float4 av = *reinterpret_cast<const float4*>(af + (size_t)ea * 32 + cl * 4);
          a0 = av.x; a1 = av.y; a2 = av.z; a3 = av.w;
        } else {
          const u16* ap = ah + (size_t)ea * 32 + cl * 4;
          a0 = bf2f(ap[0]); a1 = bf2f(ap[1]); a2 = bf2f(ap[2]); a3 = bf2f(ap[3]);
        }
        acc0[0] += s0.x * a0; acc0[1] += s0.y * a1; acc0[2] += s0.z * a1; acc0[3] += s0.w * a1;
        acc1[0] += s1.x * a2; acc1[1] += s1.y * a2; acc1[2] += s1.z * a2; acc1[3] += s1.w * a2;
        acc2[0] += s2.x * a2; acc2[1] += s2.y * a3; acc2[2] += s2.z * a3; acc2[3] += s2.w * a3;
        acc3[0] += s3.x * a3; acc3[1] += s3.y * a3; acc3[2] += s3.z * a3; acc3[3] += s3.w * a3;
      }
    }
    i += cnt;
  }
#pragma unroll
  for (int mask = 8; mask <= 32; mask <<= 1) {
#pragma unroll
    for (int j = 0; j < 4; j++) {
      acc0[j] += __shfl_xor(acc0[j], mask);
      acc1[j] += __shfl_xor(acc1[j], mask);
      acc2[j] += __shfl_xor(acc2[j], mask);
      acc3[j] += __shfl_xor(acc3[j], mask);
    }
  }
  if (grp == 0) {
    float* op = out + (size_t)n * 128 + c0;
    *reinterpret_cast<f32x4*>(op) = acc0;
    *reinterpret_cast<f32x4*>(op + 4) = acc1;
    *reinterpret_cast<f32x4*>(op + 8) = acc2;
    *reinterpret_cast<f32x4*>(op + 12) = acc3;
  }
}

static inline size_t align64(size_t x) { return (x + 63) & ~(size_t)63; }

extern "C" void kernel_launch(void* const* d_in, const int* in_sizes, int n_in,
                              void* d_out, int out_size, void* d_ws, size_t ws_size,
                              hipStream_t stream) {
  const float* edge_sh = (const float*)d_in[0];
  const float* node_feats = (const float*)d_in[1];
  const float* edge_feats = (const float*)d_in[2];
  const float* chi_s = (const float*)d_in[3];
  const float* cutoffs = (const float*)d_in[4];
  const int* senders = (const int*)d_in[5];
  const int* receivers = (const int*)d_in[6];
  const float* W1 = (const float*)d_in[7];
  const float* b1 = (const float*)d_in[8];
  const float* W2 = (const float*)d_in[9];
  const float* b2 = (const float*)d_in[10];
  const float* Wsp = (const float*)d_in[11];
  const float* bs = (const float*)d_in[12];
  const float* Wq = (const float*)d_in[13];
  const float* Wk = (const float*)d_in[14];

  const int E = in_sizes[4];
  const int N = in_sizes[1] / 256;

  char* ws = (char*)d_ws;
  u16* W1p = (u16*)(ws + 0);
  u16* W23p = (u16*)(ws + 32768);
  u16* Wqkp = (u16*)(ws + 229376);
  float* b23 = (float*)(ws + 491520);
  u16* qk = (u16*)(ws + 524288);  // N*512 bf16
  size_t qk_end = 524288 + (size_t)N * 512 * 2;

  size_t csr_bytes = align64((size_t)N * 4) * 3 + 8192 + align64(((size_t)N + 1) * 4) +
                     align64((size_t)E * 4);
  size_t need_f32 = align64(qk_end) + align64((size_t)E * 32 * 4) + csr_bytes;
  int alpha_f32 = (ws_size >= need_f32) ? 1 : 0;
  size_t alpha_bytes = (size_t)E * 32 * (alpha_f32 ? 4 : 2);

  size_t o = align64(qk_end);
  void* alpha = (void*)(ws + o);
  o = align64(o + alpha_bytes);
  int* counts = (int*)(ws + o);
  o += align64((size_t)N * 4);
  int* bsum = (int*)(ws + o);
  o += 4096;
  int* boff = (int*)(ws + o);
  o += 4096;
  int* off = (int*)(ws + o);
  o += align64(((size_t)N + 1) * 4);
  int* cursor = (int*)(ws + o);
  o += align64((size_t)N * 4);
  int* eid = (int*)(ws + o);

  const int nb_scan = (N + 1023) / 1024;

  (void)hipMemsetAsync(counts, 0, (size_t)N * 4, stream);
  pack_kernel<<<121, 256, 0, stream>>>(W1, W2, Wsp, Wq, Wk, b2, bs, W1p, W23p, Wqkp, b23);
  node_qk_kernel<<<(N + 63) / 64, 512, 0, stream>>>(node_feats, Wqkp, qk, N);
  hist_kernel<<<(E + 255) / 256, 256, 0, stream>>>(receivers, counts, E);
  scan_block_kernel<<<nb_scan, 256, 0, stream>>>(counts, bsum, N);
  scan_top_kernel<<<1, 64, 0, stream>>>(bsum, boff, nb_scan);
  finalize_kernel<<<(N + 255) / 256, 256, 0, stream>>>(counts, boff, off, cursor, N, E);
  fill_kernel<<<(E + 255) / 256, 256, 0, stream>>>(receivers, cursor, eid, E);
  edge_alpha_kernel<<<(E + 63) / 64, 512, 0, stream>>>(
      edge_feats, chi_s, cutoffs, senders, receivers, W1p, W23p, b1, b23, qk,
      alpha, alpha_f32, E);
  gather_out_kernel<<<(N + 3) / 4, 256, 0, stream>>>(edge_sh, alpha, off, eid,
                                                     (float*)d_out, N, alpha_f32);
}

// Round 19
// 381.481 us; speedup vs baseline: 1.0437x; 1.0437x over previous
//
#include <hip/hip_runtime.h>

// GeometricBlock, MI355X gfx950. CSR scatter; LDS-staged MFMA with hw-packed cvt.
// BANKED BEST (R17, 381.8us): edge_alpha = R15 (512thr/8wv, 64-edge tile, H+Abuf
// 43008B, 24 wv/CU); node_qk 8-wave low-VGPR; gather 8-group + skip-dead-loads.
// Failed variants (do not retry): XOR swizzle (R8), cross-barrier prefetch (R9/R13),
// min-waves bound (R7), chi-merge (R11), M-shrink (R14), chunk-stage (R16),
// single-buffer (R18) — phases need disjoint buffers; TLP is the only latency cover.

typedef short bf16x8 __attribute__((ext_vector_type(8)));
typedef float f32x4 __attribute__((ext_vector_type(4)));
typedef unsigned short u16;
typedef u16 u16x8 __attribute__((ext_vector_type(8)));

__device__ __forceinline__ float bf2f(u16 h) {
  return __builtin_bit_cast(float, ((unsigned)h) << 16);
}
__device__ __forceinline__ unsigned cvt_pk_bf16(float lo, float hi) {
  unsigned p;
  asm("v_cvt_pk_bf16_f32 %0, %1, %2" : "=v"(p) : "v"(lo), "v"(hi));
  return p;
}
__device__ __forceinline__ u16 f2bf_hw(float f) {
  return (u16)cvt_pk_bf16(f, f);
}
__device__ __forceinline__ float silu_fast(float x) {
  return x * __builtin_amdgcn_rcpf(1.f + __expf(-x));
}

// ---------------- pack weights to MFMA B-fragment order ---------------------
__global__ __launch_bounds__(256) void pack_kernel(
    const float* __restrict__ W1, const float* __restrict__ W2,
    const float* __restrict__ Wsp, const float* __restrict__ Wq,
    const float* __restrict__ Wk, const float* __restrict__ b2,
    const float* __restrict__ bs, u16* __restrict__ W1p,
    u16* __restrict__ W23p, u16* __restrict__ Wqkp, float* __restrict__ b23) {
  int t = blockIdx.x * 256 + threadIdx.x;
  if (t < 2048) {  // W1: K=64 (KF=2), C=256
    int lane = t & 63, kf = (t >> 6) & 1, cf = t >> 7;
    int kb = kf * 32 + ((lane >> 4) << 3), c = cf * 16 + (lane & 15);
    u16x8 o;
#pragma unroll
    for (int j = 0; j < 8; j++) o[j] = f2bf_hw(W1[(kb + j) * 256 + c]);
    *reinterpret_cast<u16x8*>(W1p + (((cf * 2 + kf) * 64 + lane) << 3)) = o;
  } else if (t < 14336) {  // W23: K=384 (KF=12), C=256
    int u = t - 2048;
    int lane = u & 63, f = u >> 6, kf = f % 12, cf = f / 12;
    int kb = kf * 32 + ((lane >> 4) << 3), c = cf * 16 + (lane & 15);
    u16x8 o;
#pragma unroll
    for (int j = 0; j < 8; j++) {
      int k = kb + j;
      float v = (k < 256) ? W2[k * 256 + c] : Wsp[(k - 256) * 256 + c];
      o[j] = f2bf_hw(v);
    }
    *reinterpret_cast<u16x8*>(W23p + (((cf * 12 + kf) * 64 + lane) << 3)) = o;
  } else if (t < 30720) {  // Wqk: K=256 (KF=8), C=512
    int u = t - 14336;
    int lane = u & 63, f = u >> 6, kf = f & 7, cf = f >> 3;
    int kb = kf * 32 + ((lane >> 4) << 3), c = cf * 16 + (lane & 15);
    u16x8 o;
#pragma unroll
    for (int j = 0; j < 8; j++) {
      int k = kb + j;
      float v = (c < 256) ? Wq[k * 256 + c] : Wk[k * 256 + (c - 256)];
      o[j] = f2bf_hw(v);
    }
    *reinterpret_cast<u16x8*>(Wqkp + (((cf * 8 + kf) * 64 + lane) << 3)) = o;
  } else if (t < 30976) {
    int c = t - 30720;
    b23[c] = b2[c] + bs[c];
  }
}

// ---------------- qk[n] = node_feats[n] @ [Wq|Wk], bf16 out -----------------
// 512 threads / 8 waves; wave owns 32 cols per nh pass (acc[4][2], low VGPR).
__global__ __launch_bounds__(512) void node_qk_kernel(
    const float* __restrict__ nf, const u16* __restrict__ Wqkp,
    u16* __restrict__ qk, int N) {
  __shared__ u16 A[64 * 264];
  const int t = threadIdx.x;
  const int nb0 = blockIdx.x * 64;
#pragma unroll
  for (int p = 0; p < 8; p++) {
    int r = p * 8 + (t >> 6), c4 = t & 63;
    int row = nb0 + r;
    float4 v = make_float4(0.f, 0.f, 0.f, 0.f);
    if (row < N) v = *reinterpret_cast<const float4*>(nf + (size_t)row * 256 + c4 * 4);
    uint2 o;
    o.x = cvt_pk_bf16(v.x, v.y);
    o.y = cvt_pk_bf16(v.z, v.w);
    *reinterpret_cast<uint2*>(&A[r * 264 + c4 * 4]) = o;
  }
  __syncthreads();
  const int lane = t & 63, wv = t >> 6;
  const int l15 = lane & 15, lhi = lane >> 4;
  for (int nh = 0; nh < 2; nh++) {
    const int colbase = nh * 256 + wv * 32;
    f32x4 acc[4][2];
#pragma unroll
    for (int m = 0; m < 4; m++)
#pragma unroll
      for (int n = 0; n < 2; n++) acc[m][n] = f32x4{0.f, 0.f, 0.f, 0.f};
#pragma unroll
    for (int kf = 0; kf < 8; kf++) {
      bf16x8 a[4];
#pragma unroll
      for (int m = 0; m < 4; m++)
        a[m] = *reinterpret_cast<const bf16x8*>(&A[(m * 16 + l15) * 264 + kf * 32 + lhi * 8]);
#pragma unroll
      for (int n = 0; n < 2; n++) {
        int cf = (colbase >> 4) + n;
        bf16x8 b = *reinterpret_cast<const bf16x8*>(Wqkp + (((cf * 8 + kf) * 64 + lane) << 3));
#pragma unroll
        for (int m = 0; m < 4; m++)
          acc[m][n] = __builtin_amdgcn_mfma_f32_16x16x32_bf16(a[m], b, acc[m][n], 0, 0, 0);
      }
    }
#pragma unroll
    for (int m = 0; m < 4; m++) {
      int row = nb0 + m * 16 + lhi * 4;
#pragma unroll
      for (int n = 0; n < 2; n++) {
        int col = colbase + n * 16 + l15;
#pragma unroll
        for (int j = 0; j < 4; j++) {
          if (row + j < N) qk[(size_t)(row + j) * 512 + col] = f2bf_hw(acc[m][n][j]);
        }
      }
    }
  }
}

// ---------------- edge alpha: GEMMs + q.w.k -> alpha[E,32] ------------------
// 64 edges/block, 512 threads / 8 waves; wave owns 32 cols (acc[4][2]). R15.
__global__ __launch_bounds__(512) void edge_alpha_kernel(
    const float* __restrict__ edge_feats, const float* __restrict__ chi_s,
    const float* __restrict__ cutoffs, const int* __restrict__ senders,
    const int* __restrict__ receivers, const u16* __restrict__ W1p,
    const u16* __restrict__ W23p, const float* __restrict__ b1,
    const float* __restrict__ b23, const u16* __restrict__ qk,
    void* __restrict__ alpha_out, int alpha_f32, int E) {
  __shared__ u16 H[64 * 264];    // hidden bf16, later w bf16; row 528B (33.8KB)
  __shared__ u16 Abuf[64 * 72];  // ef / chi-half tile, stride 72 (9.2KB)

  const int t = threadIdx.x;
  const int e0 = blockIdx.x * 64;
  const int lane = t & 63, wv = t >> 6, l15 = lane & 15, lhi = lane >> 4;
  const int koff = lhi * 8;
  const int sr = t >> 3, sc8 = (t & 7) * 8;  // staging: row sr (0..63), 8 f32
  const int se = (e0 + sr < E) ? e0 + sr : (E - 1);

  // stage edge_feats [64][64] f32 -> bf16 (each thread: 8 f32 = 2 float4)
  {
    const float* src = edge_feats + (size_t)se * 64 + sc8;
#pragma unroll
    for (int q = 0; q < 2; q++) {
      float4 v = *reinterpret_cast<const float4*>(src + q * 4);
      uint2 o;
      o.x = cvt_pk_bf16(v.x, v.y);
      o.y = cvt_pk_bf16(v.z, v.w);
      *reinterpret_cast<uint2*>(&Abuf[sr * 72 + sc8 + q * 4]) = o;
    }
  }
  __syncthreads();

  f32x4 acc[4][2];
  // ---- GEMM1: hidden = silu(ef @ W1 + b1); wave owns cols [wv*32, wv*32+32)
#pragma unroll
  for (int m = 0; m < 4; m++)
#pragma unroll
    for (int n = 0; n < 2; n++) acc[m][n] = f32x4{0.f, 0.f, 0.f, 0.f};
#pragma unroll
  for (int kf = 0; kf < 2; kf++) {
    bf16x8 a[4];
#pragma unroll
    for (int m = 0; m < 4; m++)
      a[m] = *reinterpret_cast<const bf16x8*>(&Abuf[(m * 16 + l15) * 72 + kf * 32 + koff]);
#pragma unroll
    for (int n = 0; n < 2; n++) {
      int cf = wv * 2 + n;
      bf16x8 b = *reinterpret_cast<const bf16x8*>(W1p + (((cf * 2 + kf) * 64 + lane) << 3));
#pragma unroll
      for (int m = 0; m < 4; m++)
        acc[m][n] = __builtin_amdgcn_mfma_f32_16x16x32_bf16(a[m], b, acc[m][n], 0, 0, 0);
    }
  }
  {
    float bv[2];
#pragma unroll
    for (int n = 0; n < 2; n++) bv[n] = b1[wv * 32 + n * 16 + l15];
#pragma unroll
    for (int m = 0; m < 4; m++)
#pragma unroll
      for (int n = 0; n < 2; n++) {
        int col = wv * 32 + n * 16 + l15;
#pragma unroll
        for (int jp = 0; jp < 2; jp++) {
          float x0 = silu_fast(acc[m][n][jp * 2] + bv[n]);
          float x1 = silu_fast(acc[m][n][jp * 2 + 1] + bv[n]);
          unsigned p = cvt_pk_bf16(x0, x1);
          int row = m * 16 + lhi * 4 + jp * 2;
          H[row * 264 + col] = (u16)p;
          H[(row + 1) * 264 + col] = (u16)(p >> 16);
        }
      }
  }
  __syncthreads();  // H visible; Abuf reads done -> restage
  // stage chi half0 (cols 0..63)
  {
    const float* src = chi_s + (size_t)se * 128 + sc8;
#pragma unroll
    for (int q = 0; q < 2; q++) {
      float4 v = *reinterpret_cast<const float4*>(src + q * 4);
      uint2 o;
      o.x = cvt_pk_bf16(v.x, v.y);
      o.y = cvt_pk_bf16(v.z, v.w);
      *reinterpret_cast<uint2*>(&Abuf[sr * 72 + sc8 + q * 4]) = o;
    }
  }
  __syncthreads();
  // ---- GEMM2 (hidden K=256 from H) + GEMM3 half0 (chi k 0..63)
#pragma unroll
  for (int m = 0; m < 4; m++)
#pragma unroll
    for (int n = 0; n < 2; n++) acc[m][n] = f32x4{0.f, 0.f, 0.f, 0.f};
#pragma unroll
  for (int kf = 0; kf < 8; kf++) {
    bf16x8 a[4];
#pragma unroll
    for (int m = 0; m < 4; m++)
      a[m] = *reinterpret_cast<const bf16x8*>(&H[(m * 16 + l15) * 264 + kf * 32 + koff]);
#pragma unroll
    for (int n = 0; n < 2; n++) {
      int cf = wv * 2 + n;
      bf16x8 b = *reinterpret_cast<const bf16x8*>(W23p + (((cf * 12 + kf) * 64 + lane) << 3));
#pragma unroll
      for (int m = 0; m < 4; m++)
        acc[m][n] = __builtin_amdgcn_mfma_f32_16x16x32_bf16(a[m], b, acc[m][n], 0, 0, 0);
    }
  }
#pragma unroll
  for (int kf = 0; kf < 2; kf++) {
    bf16x8 a[4];
#pragma unroll
    for (int m = 0; m < 4; m++)
      a[m] = *reinterpret_cast<const bf16x8*>(&Abuf[(m * 16 + l15) * 72 + kf * 32 + koff]);
#pragma unroll
    for (int n = 0; n < 2; n++) {
      int cf = wv * 2 + n;
      bf16x8 b = *reinterpret_cast<const bf16x8*>(W23p + (((cf * 12 + 8 + kf) * 64 + lane) << 3));
#pragma unroll
      for (int m = 0; m < 4; m++)
        acc[m][n] = __builtin_amdgcn_mfma_f32_16x16x32_bf16(a[m], b, acc[m][n], 0, 0, 0);
    }
  }
  __syncthreads();  // Abuf + H reads done
  // stage chi half1 (cols 64..127)
  {
    const float* src = chi_s + (size_t)se * 128 + 64 + sc8;
#pragma unroll
    for (int q = 0; q < 2; q++) {
      float4 v = *reinterpret_cast<const float4*>(src + q * 4);
      uint2 o;
      o.x = cvt_pk_bf16(v.x, v.y);
      o.y = cvt_pk_bf16(v.z, v.w);
      *reinterpret_cast<uint2*>(&Abuf[sr * 72 + sc8 + q * 4]) = o;
    }
  }
  __syncthreads();
  // ---- GEMM3 half1 (chi k 64..127)
#pragma unroll
  for (int kf = 0; kf < 2; kf++) {
    bf16x8 a[4];
#pragma unroll
    for (int m = 0; m < 4; m++)
      a[m] = *reinterpret_cast<const bf16x8*>(&Abuf[(m * 16 + l15) * 72 + kf * 32 + koff]);
#pragma unroll
    for (int n = 0; n < 2; n++) {
      int cf = wv * 2 + n;
      bf16x8 b = *reinterpret_cast<const bf16x8*>(W23p + (((cf * 12 + 10 + kf) * 64 + lane) << 3));
#pragma unroll
      for (int m = 0; m < 4; m++)
        acc[m][n] = __builtin_amdgcn_mfma_f32_16x16x32_bf16(a[m], b, acc[m][n], 0, 0, 0);
    }
  }
  __syncthreads();  // H reads done; safe to overwrite with w
  {
    float bv[2];
#pragma unroll
    for (int n = 0; n < 2; n++) bv[n] = b23[wv * 32 + n * 16 + l15];
#pragma unroll
    for (int m = 0; m < 4; m++)
#pragma unroll
      for (int n = 0; n < 2; n++) {
        int col = wv * 32 + n * 16 + l15;
#pragma unroll
        for (int jp = 0; jp < 2; jp++) {
          unsigned p = cvt_pk_bf16(acc[m][n][jp * 2] + bv[n], acc[m][n][jp * 2 + 1] + bv[n]);
          int row = m * 16 + lhi * 4 + jp * 2;
          H[row * 264 + col] = (u16)p;
          H[(row + 1) * 264 + col] = (u16)(p >> 16);
        }
      }
  }
  __syncthreads();
  // ---- alpha[e][h] = sum_d q*w*k * cutoff * (1/sqrt(8)) * (1/10 neighbors)
  {
    int e = t >> 3, h8 = t & 7;
    int ee = e0 + e;
    int ec = (ee < E) ? ee : (E - 1);
    int rv = receivers[ec], sd = senders[ec];
    float sc = cutoffs[ec] * 0.035355339059327376f;  // (1/sqrt(8))*(1/10)
    const u16* qrow = qk + (size_t)rv * 512;
    const u16* krow = qk + (size_t)sd * 512 + 256;
    const bool wr = (ee < E);
    float* af = (float*)alpha_out;
    u16* ah = (u16*)alpha_out;
#pragma unroll
    for (int i = 0; i < 4; i++) {
      int h = i * 8 + h8;
      u16x8 q8 = *reinterpret_cast<const u16x8*>(qrow + h * 8);
      u16x8 k8 = *reinterpret_cast<const u16x8*>(krow + h * 8);
      u16x8 w8 = *reinterpret_cast<const u16x8*>(&H[e * 264 + h * 8]);
      float s = 0.f;
#pragma unroll
      for (int d = 0; d < 8; d++) s += bf2f(q8[d]) * bf2f(w8[d]) * bf2f(k8[d]);
      s *= sc;
      if (wr) {
        if (alpha_f32) af[(size_t)ee * 32 + h] = s;
        else ah[(size_t)ee * 32 + h] = f2bf_hw(s);
      }
    }
  }
}

// ---------------- CSR build ------------------------------------------------
__global__ __launch_bounds__(256) void hist_kernel(const int* __restrict__ recv,
                                                   int* __restrict__ counts, int E) {
  int e = blockIdx.x * 256 + threadIdx.x;
  if (e < E) atomicAdd(&counts[recv[e]], 1);
}

__global__ __launch_bounds__(256) void scan_block_kernel(int* __restrict__ counts,
                                                         int* __restrict__ bsum, int N) {
  __shared__ int tmp[256];
  int t = threadIdx.x;
  int base = blockIdx.x * 1024 + t * 4;
  int v[4], p[4], tot = 0;
#pragma unroll
  for (int j = 0; j < 4; j++) {
    int n = base + j;
    v[j] = (n < N) ? counts[n] : 0;
    p[j] = tot;
    tot += v[j];
  }
  tmp[t] = tot;
  __syncthreads();
  for (int s = 1; s < 256; s <<= 1) {
    int a = (t >= s) ? tmp[t - s] : 0;
    __syncthreads();
    tmp[t] += a;
    __syncthreads();
  }
  int excl = tmp[t] - tot;
#pragma unroll
  for (int j = 0; j < 4; j++) {
    int n = base + j;
    if (n < N) counts[n] = excl + p[j];
  }
  if (t == 255) bsum[blockIdx.x] = tmp[255];
}

__global__ void scan_top_kernel(const int* __restrict__ bsum, int* __restrict__ boff, int nb) {
  if (threadIdx.x == 0 && blockIdx.x == 0) {
    int ex = 0;
    for (int b = 0; b < nb; b++) {
      boff[b] = ex;
      ex += bsum[b];
    }
  }
}

__global__ __launch_bounds__(256) void finalize_kernel(
    const int* __restrict__ partial, const int* __restrict__ boff,
    int* __restrict__ off, int* __restrict__ cursor, int N, int E) {
  int n = blockIdx.x * 256 + threadIdx.x;
  if (n < N) {
    int o = partial[n] + boff[n >> 10];
    off[n] = o;
    cursor[n] = o;
  }
  if (n == 0) off[N] = E;
}

__global__ __launch_bounds__(256) void fill_kernel(const int* __restrict__ recv,
                                                   int* __restrict__ cursor,
                                                   int* __restrict__ eid, int E) {
  int e = blockIdx.x * 256 + threadIdx.x;
  if (e < E) {
    int pos = atomicAdd(&cursor[recv[e]], 1);
    eid[pos] = e;
  }
}

// ---------------- gather: out[n] = sum_{e in CSR(n)} sh[e] * alpha[e,hd] ----
// 8 groups x 8 lanes per wave; dead groups SKIP their loads.
__global__ __launch_bounds__(256) void gather_out_kernel(
    const float* __restrict__ edge_sh, const void* __restrict__ alpha,
    const int* __restrict__ off, const int* __restrict__ eid,
    float* __restrict__ out, int N, int alpha_f32) {
  int wv = threadIdx.x >> 6, lane = threadIdx.x & 63;
  int n = blockIdx.x * 4 + wv;
  if (n >= N) return;
  int beg = off[n], end = off[n + 1];
  int grp = lane >> 3, cl = lane & 7;
  int c0 = cl * 16;
  const float* af = (const float*)alpha;
  const u16* ah = (const u16*)alpha;
  f32x4 acc0 = {0.f, 0.f, 0.f, 0.f}, acc1 = acc0, acc2 = acc0, acc3 = acc0;
  int i = beg;
  while (i < end) {
    int cnt = end - i;
    if (cnt > 64) cnt = 64;
    int ev = eid[i + ((lane < cnt) ? lane : 0)];  // one coalesced eid load
    for (int k = 0; k < cnt; k += 8) {
      int idx = k + grp;
      int ea = __shfl(ev, (idx < cnt) ? idx : 0);  // shfl outside branch
      if (idx < cnt) {
        const float* shp = edge_sh + (size_t)ea * 128 + c0;
        float4 s0 = *reinterpret_cast<const float4*>(shp);
        float4 s1 = *reinterpret_cast<const float4*>(shp + 4);
        float4 s2 = *reinterpret_cast<const float4*>(shp + 8);
        float4 s3 = *reinterpret_cast<const float4*>(shp + 12);
        float a0, a1, a2, a3;
        if (alpha_f32) {
          float4 av = *reinterpret_cast<const float4*>(af + (size_t)ea * 32 + cl * 4);
          a0 = av.x; a1 = av.y; a2 = av.z; a3 = av.w;
        } else {
          const u16* ap = ah + (size_t)ea * 32 + cl * 4;
          a0 = bf2f(ap[0]); a1 = bf2f(ap[1]); a2 = bf2f(ap[2]); a3 = bf2f(ap[3]);
        }
        acc0[0] += s0.x * a0; acc0[1] += s0.y * a1; acc0[2] += s0.z * a1; acc0[3] += s0.w * a1;
        acc1[0] += s1.x * a2; acc1[1] += s1.y * a2; acc1[2] += s1.z * a2; acc1[3] += s1.w * a2;
        acc2[0] += s2.x * a2; acc2[1] += s2.y * a3; acc2[2] += s2.z * a3; acc2[3] += s2.w * a3;
        acc3[0] += s3.x * a3; acc3[1] += s3.y * a3; acc3[2] += s3.z * a3; acc3[3] += s3.w * a3;
      }
    }
    i += cnt;
  }
#pragma unroll
  for (int mask = 8; mask <= 32; mask <<= 1) {
#pragma unroll
    for (int j = 0; j < 4; j++) {
      acc0[j] += __shfl_xor(acc0[j], mask);
      acc1[j] += __shfl_xor(acc1[j], mask);
      acc2[j] += __shfl_xor(acc2[j], mask);
      acc3[j] += __shfl_xor(acc3[j], mask);
    }
  }
  if (grp == 0) {
    float* op = out + (size_t)n * 128 + c0;
    *reinterpret_cast<f32x4*>(op) = acc0;
    *reinterpret_cast<f32x4*>(op + 4) = acc1;
    *reinterpret_cast<f32x4*>(op + 8) = acc2;
    *reinterpret_cast<f32x4*>(op + 12) = acc3;
  }
}

static inline size_t align64(size_t x) { return (x + 63) & ~(size_t)63; }

extern "C" void kernel_launch(void* const* d_in, const int* in_sizes, int n_in,
                              void* d_out, int out_size, void* d_ws, size_t ws_size,
                              hipStream_t stream) {
  const float* edge_sh = (const float*)d_in[0];
  const float* node_feats = (const float*)d_in[1];
  const float* edge_feats = (const float*)d_in[2];
  const float* chi_s = (const float*)d_in[3];
  const float* cutoffs = (const float*)d_in[4];
  const int* senders = (const int*)d_in[5];
  const int* receivers = (const int*)d_in[6];
  const float* W1 = (const float*)d_in[7];
  const float* b1 = (const float*)d_in[8];
  const float* W2 = (const float*)d_in[9];
  const float* b2 = (const float*)d_in[10];
  const float* Wsp = (const float*)d_in[11];
  const float* bs = (const float*)d_in[12];
  const float* Wq = (const float*)d_in[13];
  const float* Wk = (const float*)d_in[14];

  const int E = in_sizes[4];
  const int N = in_sizes[1] / 256;

  char* ws = (char*)d_ws;
  u16* W1p = (u16*)(ws + 0);
  u16* W23p = (u16*)(ws + 32768);
  u16* Wqkp = (u16*)(ws + 229376);
  float* b23 = (float*)(ws + 491520);
  u16* qk = (u16*)(ws + 524288);  // N*512 bf16
  size_t qk_end = 524288 + (size_t)N * 512 * 2;

  size_t csr_bytes = align64((size_t)N * 4) * 3 + 8192 + align64(((size_t)N + 1) * 4) +
                     align64((size_t)E * 4);
  size_t need_f32 = align64(qk_end) + align64((size_t)E * 32 * 4) + csr_bytes;
  int alpha_f32 = (ws_size >= need_f32) ? 1 : 0;
  size_t alpha_bytes = (size_t)E * 32 * (alpha_f32 ? 4 : 2);

  size_t o = align64(qk_end);
  void* alpha = (void*)(ws + o);
  o = align64(o + alpha_bytes);
  int* counts = (int*)(ws + o);
  o += align64((size_t)N * 4);
  int* bsum = (int*)(ws + o);
  o += 4096;
  int* boff = (int*)(ws + o);
  o += 4096;
  int* off = (int*)(ws + o);
  o += align64(((size_t)N + 1) * 4);
  int* cursor = (int*)(ws + o);
  o += align64((size_t)N * 4);
  int* eid = (int*)(ws + o);

  const int nb_scan = (N + 1023) / 1024;

  (void)hipMemsetAsync(counts, 0, (size_t)N * 4, stream);
  pack_kernel<<<121, 256, 0, stream>>>(W1, W2, Wsp, Wq, Wk, b2, bs, W1p, W23p, Wqkp, b23);
  node_qk_kernel<<<(N + 63) / 64, 512, 0, stream>>>(node_feats, Wqkp, qk, N);
  hist_kernel<<<(E + 255) / 256, 256, 0, stream>>>(receivers, counts, E);
  scan_block_kernel<<<nb_scan, 256, 0, stream>>>(counts, bsum, N);
  scan_top_kernel<<<1, 64, 0, stream>>>(bsum, boff, nb_scan);
  finalize_kernel<<<(N + 255) / 256, 256, 0, stream>>>(counts, boff, off, cursor, N, E);
  fill_kernel<<<(E + 255) / 256, 256, 0, stream>>>(receivers, cursor, eid, E);
  edge_alpha_kernel<<<(E + 63) / 64, 512, 0, stream>>>(
      edge_feats, chi_s, cutoffs, senders, receivers, W1p, W23p, b1, b23, qk,
      alpha, alpha_f32, E);
  gather_out_kernel<<<(N + 3) / 4, 256, 0, stream>>>(edge_sh, alpha, off, eid,
                                                     (float*)d_out, N, alpha_f32);
}